// Round 1
// baseline (2909.220 us; speedup 1.0000x reference)
//
#include <hip/hip_runtime.h>
#include <hip/hip_bf16.h>

// Problem constants
#define S_LEN 128
#define B_SZ  128
#define H_SZ  512
#define V_SZ  10000
#define VP_SZ 10240   // V padded to 128-multiple for GEMM tiles

typedef _Float16 half8 __attribute__((ext_vector_type(8)));
typedef float floatx4 __attribute__((ext_vector_type(4)));

__device__ __forceinline__ floatx4 mfma16(half8 a, half8 b, floatx4 c) {
    return __builtin_amdgcn_mfma_f32_16x16x32_f16(a, b, c, 0, 0, 0);
}

// Fast tanh: clamp keeps exp in range; |err| ~1e-6 << fp16 noise.
__device__ __forceinline__ float fast_tanh(float x) {
    x = fminf(15.f, fmaxf(-15.f, x));
    float e = __expf(2.f * x);
    return (e - 1.f) / (e + 1.f);
}

// ---------------- small prep kernels ----------------
__global__ void cast_f16_kernel(const float* __restrict__ src,
                                _Float16* __restrict__ dst, int n) {
    int i = blockIdx.x * 256 + threadIdx.x;
    if (i < n) dst[i] = (_Float16)src[i];
}

__global__ void build_wout_kernel(const float* __restrict__ W,
                                  _Float16* __restrict__ dst,
                                  unsigned* __restrict__ cnt) {
    int i = blockIdx.x * 256 + threadIdx.x;
    if (i < VP_SZ * H_SZ) {
        int row = i >> 9;
        int k = i & 511;
        dst[i] = (row < V_SZ) ? (_Float16)W[(size_t)row * H_SZ + k] : (_Float16)0.f;
    }
    if (i < 16) cnt[i] = 0;   // zero sync counters (ws is poisoned each call)
}

// ---------------- generic fp16 GEMM: C[m,n] = sum_k A[m,k]*Bt[n,k] + bias[n] ----------------
// 128x128 tile, BK=64, padded LDS (2-way-free bank pattern), 2x2 waves, 4x4 MFMA tiles/wave.
#define TK 64
#define LDSS 72   // 64 + 8 halves pad -> ds_read_b128 2-way conflict only (free)

__global__ __launch_bounds__(256) void gemm_f16_kernel(
    const _Float16* __restrict__ A, int lda, int M,
    const _Float16* __restrict__ Bt, int ldb,
    float* __restrict__ C, long ldc, int Nstore,
    const float* __restrict__ bias, int K)
{
    __shared__ __align__(16) _Float16 sA[128 * LDSS];
    __shared__ __align__(16) _Float16 sB[128 * LDSS];
    const int m0 = blockIdx.x * 128;
    const int n0 = blockIdx.y * 128;
    const int tid = threadIdx.x;
    const int lane = tid & 63;
    const int wave = tid >> 6;
    const int wr = wave >> 1, wc = wave & 1;
    const int quad = lane >> 4, l16 = lane & 15;

    floatx4 acc[4][4];
#pragma unroll
    for (int i = 0; i < 4; ++i)
#pragma unroll
        for (int j = 0; j < 4; ++j) acc[i][j] = (floatx4){0.f, 0.f, 0.f, 0.f};

    for (int k0 = 0; k0 < K; k0 += TK) {
#pragma unroll
        for (int r = 0; r < 4; ++r) {
            int idx = r * 256 + tid;           // 0..1023 -> 128 rows x 8 chunks
            int row = idx >> 3;
            int kc = (idx & 7) * 8;
            int ga = m0 + row; if (ga >= M) ga = M - 1;   // clamp (stores guarded)
            half8 va = *(const half8*)(A + (size_t)ga * lda + k0 + kc);
            *(half8*)(sA + row * LDSS + kc) = va;
            half8 vb = *(const half8*)(Bt + (size_t)(n0 + row) * ldb + k0 + kc);
            *(half8*)(sB + row * LDSS + kc) = vb;
        }
        __syncthreads();
#pragma unroll
        for (int ks = 0; ks < TK; ks += 32) {
            half8 af[4], bf[4];
#pragma unroll
            for (int i = 0; i < 4; ++i)
                af[i] = *(const half8*)(sA + (wr * 64 + i * 16 + l16) * LDSS + ks + quad * 8);
#pragma unroll
            for (int j = 0; j < 4; ++j)
                bf[j] = *(const half8*)(sB + (wc * 64 + j * 16 + l16) * LDSS + ks + quad * 8);
#pragma unroll
            for (int i = 0; i < 4; ++i)
#pragma unroll
                for (int j = 0; j < 4; ++j)
                    acc[i][j] = mfma16(af[i], bf[j], acc[i][j]);
        }
        __syncthreads();
    }
    // epilogue: D mapping col=lane&15, row=quad*4+reg (dtype-independent, m89/m101)
#pragma unroll
    for (int j = 0; j < 4; ++j) {
        int colg = n0 + wc * 64 + j * 16 + l16;
        if (colg >= Nstore) continue;
        float bb = bias[colg];
#pragma unroll
        for (int i = 0; i < 4; ++i) {
#pragma unroll
            for (int r = 0; r < 4; ++r) {
                int rowg = m0 + wr * 64 + i * 16 + quad * 4 + r;
                if (rowg < M) C[(size_t)rowg * ldc + colg] = acc[i][j][r] + bb;
            }
        }
    }
}

// ---------------- persistent recurrence kernel ----------------
// Grid: 128 wgs = layer(2) x batch-group(8, 16 rows) x H-slice(8, 64 cols).
// Weight B-frags pinned in VGPRs; h exchanged through write-once global slots;
// device-scope counter sync (release RMW / acquire spin + agent fences).
// Layer 0 never waits on layer 1 -> deadlock-free; 128 wgs always co-resident.
__device__ __forceinline__ void wait_ge(unsigned* p, unsigned v) {
    while (__hip_atomic_load(p, __ATOMIC_ACQUIRE, __HIP_MEMORY_SCOPE_AGENT) < v)
        __builtin_amdgcn_s_sleep(1);
}

__global__ __launch_bounds__(256, 1) void rnn_persistent(
    const int* __restrict__ tok, const float* __restrict__ emb2,
    const _Float16* __restrict__ wih16, const _Float16* __restrict__ whh16,
    const float* __restrict__ b_hh,
    _Float16* __restrict__ hs0, _Float16* __restrict__ hs1,
    float* __restrict__ hfinal, unsigned* __restrict__ cnt)
{
    const int wg = blockIdx.x;
    const int layer = wg >> 6;
    const int bg = (wg >> 3) & 7;
    const int hw = wg & 7;
    const int tid = threadIdx.x;
    const int lane = tid & 63;
    const int wave = tid >> 6;
    const int quad = lane >> 4, l16 = lane & 15;
    const int b0 = bg * 16;
    const int col = hw * 64 + wave * 16 + l16;   // this lane's output column

    // Preload weight B-fragments: B[k][n]=W[n][k] -> lane n=l16 reads row `col`, k=quad*8+.. contiguous 16B
    half8 bf_hh[16];
    const _Float16* whh = whh16 + (size_t)layer * H_SZ * H_SZ + (size_t)col * H_SZ;
#pragma unroll
    for (int kk = 0; kk < 16; ++kk)
        bf_hh[kk] = *(const half8*)(whh + kk * 32 + quad * 8);
    half8 bf_ih[16];
    if (layer == 1) {
        const _Float16* wih = wih16 + (size_t)H_SZ * H_SZ + (size_t)col * H_SZ;
#pragma unroll
        for (int kk = 0; kk < 16; ++kk)
            bf_ih[kk] = *(const half8*)(wih + kk * 32 + quad * 8);
    }
    const float bias1 = (layer == 1) ? b_hh[H_SZ + col] : 0.f;

    unsigned* my_cnt = cnt + layer * 8 + bg;
    unsigned* dep_cnt = cnt + bg;                 // layer-0 counter, same batch group
    const int rowb = b0 + quad * 4;               // acc rows rowb..rowb+3

    for (int t = 0; t < S_LEN; ++t) {
        if (tid == 0) {
            if (layer == 0) {
                if (t > 0) wait_ge(my_cnt, 8u * (unsigned)t);
            } else {
                wait_ge(dep_cnt, 8u * (unsigned)(t + 1));   // h0[t] published
                if (t > 0) wait_ge(my_cnt, 8u * (unsigned)t);
            }
        }
        __syncthreads();
        __builtin_amdgcn_fence(__ATOMIC_ACQUIRE, "agent");  // invalidate L1/L2 before reading peers' data

        floatx4 acc;
        if (layer == 0) {
            floatx4 a0, a1 = (floatx4){0.f, 0.f, 0.f, 0.f};
#pragma unroll
            for (int r = 0; r < 4; ++r) {
                int tk = tok[t * B_SZ + rowb + r];
                a0[r] = emb2[(size_t)tk * H_SZ + col];      // includes b_hh[0]
            }
            const _Float16* hprev = hs0 + (size_t)t * B_SZ * H_SZ + (size_t)(b0 + l16) * H_SZ;
#pragma unroll
            for (int kk = 0; kk < 8; ++kk) {                // two chains hide MFMA dep latency
                half8 af0 = *(const half8*)(hprev + kk * 32 + quad * 8);
                half8 af1 = *(const half8*)(hprev + (kk + 8) * 32 + quad * 8);
                a0 = mfma16(af0, bf_hh[kk], a0);
                a1 = mfma16(af1, bf_hh[kk + 8], a1);
            }
            acc = a0 + a1;
        } else {
            floatx4 a0 = (floatx4){bias1, bias1, bias1, bias1};
            floatx4 a1 = (floatx4){0.f, 0.f, 0.f, 0.f};
            floatx4 a2 = (floatx4){0.f, 0.f, 0.f, 0.f};
            floatx4 a3 = (floatx4){0.f, 0.f, 0.f, 0.f};
            const _Float16* h0t = hs0 + (size_t)(t + 1) * B_SZ * H_SZ + (size_t)(b0 + l16) * H_SZ;
            const _Float16* h1p = hs1 + (size_t)t * B_SZ * H_SZ + (size_t)(b0 + l16) * H_SZ;
#pragma unroll
            for (int kk = 0; kk < 8; ++kk) {                // four chains
                a0 = mfma16(*(const half8*)(h0t + kk * 32 + quad * 8), bf_ih[kk], a0);
                a1 = mfma16(*(const half8*)(h0t + (kk + 8) * 32 + quad * 8), bf_ih[kk + 8], a1);
                a2 = mfma16(*(const half8*)(h1p + kk * 32 + quad * 8), bf_hh[kk], a2);
                a3 = mfma16(*(const half8*)(h1p + (kk + 8) * 32 + quad * 8), bf_hh[kk + 8], a3);
            }
            acc = (a0 + a1) + (a2 + a3);
        }

        _Float16* hdst = (layer ? hs1 : hs0) + (size_t)(t + 1) * B_SZ * H_SZ;
        float hv[4];
#pragma unroll
        for (int r = 0; r < 4; ++r) hv[r] = fast_tanh(acc[r]);
#pragma unroll
        for (int r = 0; r < 4; ++r)
            hdst[(size_t)(rowb + r) * H_SZ + col] = (_Float16)hv[r];
        if (t == S_LEN - 1) {
#pragma unroll
            for (int r = 0; r < 4; ++r)
                hfinal[((size_t)layer * B_SZ + rowb + r) * H_SZ + col] = hv[r];
        }

        __syncthreads();   // compiler drains vmcnt(0) before s_barrier -> all wg stores in L2
        if (tid == 0)      // release RMW: writes back L2 (cross-XCD visible), then bump
            __hip_atomic_fetch_add(my_cnt, 1u, __ATOMIC_RELEASE, __HIP_MEMORY_SCOPE_AGENT);
    }
}

// ---------------- launch ----------------
extern "C" void kernel_launch(void* const* d_in, const int* in_sizes, int n_in,
                              void* d_out, int out_size, void* d_ws, size_t ws_size,
                              hipStream_t stream) {
    const int*   tok    = (const int*)d_in[0];
    const float* hidden = (const float*)d_in[1];
    const float* emb    = (const float*)d_in[2];
    const float* W_ih   = (const float*)d_in[3];
    const float* W_hh   = (const float*)d_in[4];
    const float* b_hh   = (const float*)d_in[5];
    const float* W_out  = (const float*)d_in[6];
    const float* b_out  = (const float*)d_in[7];
    float* out = (float*)d_out;

    char* ws = (char*)d_ws;
    size_t off = 0;
    auto alloc = [&](size_t bytes) -> void* {
        void* p = ws + off;
        off += (bytes + 255) & ~(size_t)255;
        return p;
    };
    _Float16* emb16  = (_Float16*)alloc((size_t)V_SZ * H_SZ * 2);
    _Float16* wih16  = (_Float16*)alloc((size_t)2 * H_SZ * H_SZ * 2);
    _Float16* whh16  = (_Float16*)alloc((size_t)2 * H_SZ * H_SZ * 2);
    _Float16* wout16 = (_Float16*)alloc((size_t)VP_SZ * H_SZ * 2);
    float*    emb2   = (float*)alloc((size_t)V_SZ * H_SZ * 4);
    _Float16* hs0    = (_Float16*)alloc((size_t)(S_LEN + 1) * B_SZ * H_SZ * 2);
    _Float16* hs1    = (_Float16*)alloc((size_t)(S_LEN + 1) * B_SZ * H_SZ * 2);
    unsigned* cnt    = (unsigned*)alloc(64);
    // total ws use ~77 MB

    cast_f16_kernel<<<dim3((V_SZ * H_SZ + 255) / 256), dim3(256), 0, stream>>>(emb, emb16, V_SZ * H_SZ);
    cast_f16_kernel<<<dim3((2 * H_SZ * H_SZ + 255) / 256), dim3(256), 0, stream>>>(W_ih, wih16, 2 * H_SZ * H_SZ);
    cast_f16_kernel<<<dim3((2 * H_SZ * H_SZ + 255) / 256), dim3(256), 0, stream>>>(W_hh, whh16, 2 * H_SZ * H_SZ);
    cast_f16_kernel<<<dim3((B_SZ * H_SZ + 255) / 256), dim3(256), 0, stream>>>(hidden, hs0, B_SZ * H_SZ);
    cast_f16_kernel<<<dim3((B_SZ * H_SZ + 255) / 256), dim3(256), 0, stream>>>(hidden + (size_t)B_SZ * H_SZ, hs1, B_SZ * H_SZ);
    build_wout_kernel<<<dim3((VP_SZ * H_SZ + 255) / 256), dim3(256), 0, stream>>>(W_out, wout16, cnt);

    // emb2[v,:] = emb[v,:] @ W_ih[0].T + b_hh[0]  (M=10000, N=512, K=512)
    gemm_f16_kernel<<<dim3(79, 4), dim3(256), 0, stream>>>(
        emb16, H_SZ, V_SZ, wih16, H_SZ, emb2, (long)H_SZ, H_SZ, b_hh, H_SZ);

    // full recurrence (both layers, pipelined), writes hs0/hs1 slots 1..128 and h_final
    rnn_persistent<<<dim3(128), dim3(256), 0, stream>>>(
        tok, emb2, wih16, whh16, b_hh, hs0, hs1,
        out + (size_t)S_LEN * B_SZ * V_SZ, cnt);

    // logits[t*B+b, :] = h1[t,b,:] @ W_out.T + b_out  (M=16384, N=10240->10000, K=512)
    gemm_f16_kernel<<<dim3(128, 80), dim3(256), 0, stream>>>(
        hs1 + (size_t)B_SZ * H_SZ, H_SZ, S_LEN * B_SZ, wout16, H_SZ,
        out, (long)V_SZ, V_SZ, b_out, H_SZ);
}